// Round 5
// baseline (1504.075 us; speedup 1.0000x reference)
//
#include <hip/hip_runtime.h>
#include <math.h>

#define T_STEPS 8
#define HW 4096
#define XSTR 192                    // XT channel stride (fixed, max cin)
#define FR_ROW 4352                 // convx u16 per (img,row)

typedef unsigned short u16;
typedef __attribute__((ext_vector_type(8))) short short8;
typedef __attribute__((ext_vector_type(4))) short short4v;
typedef __attribute__((ext_vector_type(4))) float f32x4;

__device__ __forceinline__ u16 f2bf(float f) {
    unsigned u = __builtin_bit_cast(unsigned, f);
    u += 0x7fffu + ((u >> 16) & 1u);
    return (u16)(u >> 16);
}
__device__ __forceinline__ float bf2f(u16 h) {
    unsigned u = ((unsigned)h) << 16;
    return __builtin_bit_cast(float, u);
}
__device__ __forceinline__ float ftanh(float x) {
    float e = __expf(2.f * x);
    return 1.f - 2.f * __builtin_amdgcn_rcpf(e + 1.f);
}
__device__ __forceinline__ float fsigm(float x) {
    return __builtin_amdgcn_rcpf(1.f + __expf(-x));
}

// grid-wide barrier: monotone counter, device scope (no reset race)
__device__ __forceinline__ void gbar(unsigned* bar, unsigned target) {
    __syncthreads();
    if (threadIdx.x == 0) {
        __threadfence();
        __hip_atomic_fetch_add(bar, 1u, __ATOMIC_ACQ_REL, __HIP_MEMORY_SCOPE_AGENT);
        while (__hip_atomic_load(bar, __ATOMIC_ACQUIRE, __HIP_MEMORY_SCOPE_AGENT) < target)
            __builtin_amdgcn_s_sleep(8);
    }
    __syncthreads();
}

// ---------------------------------------------------------------------------
// l0 only: fp32 x [img][32][64][64] -> bf16 XT[img][66][66][192] ch 0..31
// ---------------------------------------------------------------------------
__global__ __launch_bounds__(256) void transpose_halo(
    const float* __restrict__ src, u16* __restrict__ XT, int src_ctot)
{
    __shared__ float tile[32][257];
    const int img = blockIdx.z;
    const int px0 = blockIdx.x * 256;
    const float* s = src + (size_t)img * src_ctot * HW + px0;
    #pragma unroll
    for (int c = 0; c < 32; ++c)
        tile[c][threadIdx.x] = s[(size_t)c * HW + threadIdx.x];
    __syncthreads();
    const int c = threadIdx.x & 31, pb = threadIdx.x >> 5;
    const int r0 = px0 >> 6;
    for (int p = pb; p < 256; p += 8) {
        int row = r0 + (p >> 6), col = p & 63;
        XT[((size_t)img * 4356 + (row + 1) * 66 + col + 1) * XSTR + c] = f2bf(tile[c][p]);
    }
}

// ---------------------------------------------------------------------------
// Pack weights: Wr[dir][tap][80][ci_total] bf16 (rows >= 65 zeroed)
// ---------------------------------------------------------------------------
__global__ __launch_bounds__(256) void prep_w(
    const float* __restrict__ wf, const float* __restrict__ wb,
    u16* __restrict__ Wr, int ci_total)
{
    int idx = blockIdx.x * 256 + threadIdx.x;
    int total = 2 * 9 * 80 * ci_total;
    if (idx >= total) return;
    int ci = idx % ci_total;
    int rest = idx / ci_total;
    int co = rest % 80; rest /= 80;
    int tap = rest % 9;
    int dir = rest / 9;
    const float* w = dir ? wb : wf;
    float v = (co < 65) ? w[((size_t)co * ci_total + ci) * 9 + tap] : 0.f;
    Wr[idx] = f2bf(v);
}

// ---------------------------------------------------------------------------
// MFMA x-conv, LDS-staged, dir-paired z order (z = img*2 + dir -> same XCD)
// ---------------------------------------------------------------------------
__global__ __launch_bounds__(256, 4) void convx_mfma(
    const u16* __restrict__ XT, const u16* __restrict__ Wr,
    const float* __restrict__ b_f, const float* __restrict__ b_b,
    u16* __restrict__ convx, int cin, int ci_total)
{
    __shared__ u16 xs[6 * 66 * 32];
    const int tid = threadIdx.x;
    const int l = tid & 63, wv = tid >> 6;
    const int g = l >> 4, ln16 = l & 15;
    const int z = blockIdx.z;
    const int img = z >> 1, dir = z & 1;
    const int r0  = blockIdx.x * 4;
    const int orow = r0 + wv;

    const float* bias = dir ? b_b : b_f;
    f32x4 acc[5][4];
    #pragma unroll
    for (int mt = 0; mt < 5; ++mt)
        #pragma unroll
        for (int r = 0; r < 4; ++r) {
            int co = mt * 16 + g * 4 + r;
            float bv = (co < 65) ? bias[co] : 0.f;
            #pragma unroll
            for (int nt = 0; nt < 4; ++nt) acc[mt][nt][r] = bv;
        }

    const u16* wdir = Wr + (size_t)dir * 9 * 80 * ci_total + g * 8;
    const u16* xim  = XT + (size_t)img * 4356 * XSTR;

    for (int ch = 0; ch < cin; ch += 32) {
        __syncthreads();
        #pragma unroll
        for (int k = 0; k < 7; ++k) {
            int idx = k * 256 + tid;
            if (idx < 1584) {
                int seg = idx & 3;
                int pr  = idx >> 2;
                short8 v = *(const short8*)(xim + (size_t)(r0 * 66 + pr) * XSTR + ch + seg * 8);
                *(short8*)(xs + (size_t)idx * 8) = v;
            }
        }
        __syncthreads();

        #pragma unroll
        for (int ky = 0; ky < 3; ++ky) {
            #pragma unroll
            for (int kx = 0; kx < 3; ++kx) {
                const int tap = ky * 3 + kx;
                const u16* xb = xs + ((size_t)((wv + ky) * 66 + ln16 + kx)) * 32 + g * 8;
                short8 bv0 = *(const short8*)(xb);
                short8 bv1 = *(const short8*)(xb + 16 * 32);
                short8 bv2 = *(const short8*)(xb + 32 * 32);
                short8 bv3 = *(const short8*)(xb + 48 * 32);
                const u16* wb_ = wdir + ((size_t)tap * 80 + ln16) * ci_total + ch;
                #pragma unroll
                for (int mt = 0; mt < 5; ++mt) {
                    short8 af = *(const short8*)(wb_ + (size_t)mt * 16 * ci_total);
                    acc[mt][0] = __builtin_amdgcn_mfma_f32_16x16x32_bf16(af, bv0, acc[mt][0], 0, 0, 0);
                    acc[mt][1] = __builtin_amdgcn_mfma_f32_16x16x32_bf16(af, bv1, acc[mt][1], 0, 0, 0);
                    acc[mt][2] = __builtin_amdgcn_mfma_f32_16x16x32_bf16(af, bv2, acc[mt][2], 0, 0, 0);
                    acc[mt][3] = __builtin_amdgcn_mfma_f32_16x16x32_bf16(af, bv3, acc[mt][3], 0, 0, 0);
                }
            }
        }
    }

    const int zimg = dir * 32 + img;
    u16* cb = convx + ((size_t)zimg * 64 + orow) * FR_ROW;
    #pragma unroll
    for (int mt = 0; mt < 4; ++mt)
        #pragma unroll
        for (int nt = 0; nt < 4; ++nt) {
            short4v pk;
            #pragma unroll
            for (int r = 0; r < 4; ++r) pk[r] = (short)f2bf(acc[mt][nt][r]);
            *(short4v*)(cb + (size_t)(nt * 4 + mt) * 256 + l * 4) = pk;
        }
    if (g == 0) {
        #pragma unroll
        for (int nt = 0; nt < 4; ++nt) {
            short4v pk;
            #pragma unroll
            for (int r = 0; r < 4; ++r) pk[r] = (short)f2bf(acc[4][nt][r]);
            *(short4v*)(cb + 4096 + nt * 64 + ln16 * 4) = pk;
        }
    }
}

// ---------------------------------------------------------------------------
// Persistent recurrent kernel: all 8 steps in one launch (grid barrier).
// Block = 4 waves (2 rows x 2 col-halves) per (z = dir*4+b, row-block).
// Writes h -> out fp32 (+XT bf16 slice for next layer), c -> cT ping-pong.
// ---------------------------------------------------------------------------
__global__ __launch_bounds__(256) void rec_persist(
    u16* __restrict__ cT_a, u16* __restrict__ cT_b,
    const u16* __restrict__ Wr, const u16* __restrict__ convx,
    float* __restrict__ out_t, float* __restrict__ lrh,
    float* __restrict__ lrc, float* __restrict__ lrg,
    u16* __restrict__ XT, unsigned* __restrict__ bar,
    int cin, int ci_total, int layer)
{
    __shared__ u16 wlds[45 * 64 * 8];   // [tap*5+mt][lane][8] = 46080 B
    const int tid = threadIdx.x;
    const int l = tid & 63, wv = tid >> 6;
    const int g = l >> 4, ln16 = l & 15;
    const int bid = blockIdx.x;
    const int z = bid >> 5;             // dir*4 + b
    const int xb = bid & 31;
    const int dir = z >> 2, b = z & 3;
    const int row  = xb * 2 + (wv >> 1);
    const int nb   = (wv & 1) * 2;
    const int col0 = nb * 16;

    // stage this dir's c-part weights to LDS (reused across all 8 steps)
    const u16* wsrc = Wr + (size_t)dir * 9 * 80 * ci_total + cin;
    for (int i = tid; i < 2880; i += 256) {
        int fm = i >> 6, ln = i & 63;
        int tap = fm / 5, mt = fm - tap * 5;
        int co = mt * 16 + (ln & 15);
        short8 v = *(const short8*)(wsrc + (size_t)(tap * 80 + co) * ci_total + (ln >> 4) * 8);
        *(short8*)(wlds + (size_t)i * 8) = v;
    }
    __syncthreads();

    #pragma unroll 1
    for (int s = 0; s < 8; ++s) {
        const u16* cp_in = (s & 1) ? cT_b : cT_a;
        u16* cp_out      = (s & 1) ? cT_a : cT_b;
        const int t = dir ? (7 - s) : s;
        const int zimg = dir * 32 + t * 4 + b;

        // init acc from convx fragments
        const u16* cxb = convx + ((size_t)zimg * 64 + row) * FR_ROW;
        f32x4 acc[5][2];
        #pragma unroll
        for (int mt = 0; mt < 4; ++mt)
            #pragma unroll
            for (int nt = 0; nt < 2; ++nt) {
                short4v pk = *(const short4v*)(cxb + (size_t)((nb + nt) * 4 + mt) * 256 + l * 4);
                #pragma unroll
                for (int r = 0; r < 4; ++r) acc[mt][nt][r] = bf2f((u16)pk[r]);
            }
        #pragma unroll
        for (int nt = 0; nt < 2; ++nt) {
            if (g == 0) {
                short4v pk = *(const short4v*)(cxb + 4096 + (nb + nt) * 64 + ln16 * 4);
                #pragma unroll
                for (int r = 0; r < 4; ++r) acc[4][nt][r] = bf2f((u16)pk[r]);
            } else {
                #pragma unroll
                for (int r = 0; r < 4; ++r) acc[4][nt][r] = 0.f;
            }
        }

        // conv over c_prev (K=32, 9 taps), weights from LDS
        const u16* cim = cp_in + (size_t)z * 4356 * 32 + g * 8;
        #pragma unroll
        for (int ky = 0; ky < 3; ++ky) {
            #pragma unroll
            for (int kx = 0; kx < 3; ++kx) {
                const int tap = ky * 3 + kx;
                const u16* xb_ = cim + (size_t)((row + ky) * 66 + col0 + ln16 + kx) * 32;
                short8 bv0 = *(const short8*)(xb_);
                short8 bv1 = *(const short8*)(xb_ + 16 * 32);
                #pragma unroll
                for (int mt = 0; mt < 5; ++mt) {
                    short8 af = *(const short8*)(wlds + (size_t)((tap * 5 + mt) * 64 + l) * 8);
                    acc[mt][0] = __builtin_amdgcn_mfma_f32_16x16x32_bf16(af, bv0, acc[mt][0], 0, 0, 0);
                    acc[mt][1] = __builtin_amdgcn_mfma_f32_16x16x32_bf16(af, bv1, acc[mt][1], 0, 0, 0);
                }
            }
        }

        const bool last_f = (dir == 0) && (s == 7);
        float val[2], gv[2];
        #pragma unroll
        for (int nt = 0; nt < 2; ++nt) {
            val[nt] = fsigm(ftanh(acc[4][nt][0]));
            gv[nt]  = __shfl(val[nt], ln16);
        }

        const size_t obase = (size_t)(t * 4 + b) * 256 + 64 * layer + dir * 32;
        const int chb = 64 * layer + dir * 32;
        #pragma unroll
        for (int mt = 0; mt < 2; ++mt)
            #pragma unroll
            for (int nt = 0; nt < 2; ++nt) {
                int px = row * 64 + col0 + nt * 16 + ln16;
                short4v pkh;
                #pragma unroll
                for (int r = 0; r < 4; ++r) {
                    int co = mt * 16 + g * 4 + r;
                    float v = ftanh(acc[mt][nt][r]);
                    out_t[(obase + co) * HW + px] = v;
                    pkh[r] = (short)f2bf(v);
                    if (last_f) lrh[((size_t)(layer * 4 + b) * 32 + co) * HW + px] = v;
                }
                if (layer < 3)
                    *(short4v*)(XT + ((size_t)(t * 4 + b) * 4356 + (row + 1) * 66 +
                                      (col0 + nt * 16 + ln16 + 1)) * XSTR + chb + mt * 16 + g * 4) = pkh;
            }
        #pragma unroll
        for (int mt = 2; mt < 4; ++mt)
            #pragma unroll
            for (int nt = 0; nt < 2; ++nt) {
                short4v pk;
                #pragma unroll
                for (int r = 0; r < 4; ++r) {
                    int k = (mt - 2) * 16 + g * 4 + r;
                    float c = gv[nt] * ftanh(acc[mt][nt][r]);
                    pk[r] = (short)f2bf(c);
                    if (last_f)
                        lrc[((size_t)(layer * 4 + b) * 32 + k) * HW + row * 64 + col0 + nt * 16 + ln16] = c;
                }
                int colh = col0 + nt * 16 + ln16 + 1;
                *(short4v*)(cp_out + ((size_t)z * 4356 + (row + 1) * 66 + colh) * 32 + (mt - 2) * 16 + g * 4) = pk;
            }
        if (last_f && g == 0) {
            #pragma unroll
            for (int nt = 0; nt < 2; ++nt)
                lrg[(size_t)(layer * 4 + b) * HW + row * 64 + col0 + nt * 16 + ln16] = val[nt];
        }

        if (s < 7) gbar(bar, 256u * (unsigned)(s + 1));
    }
}

extern "C" void kernel_launch(void* const* d_in, const int* in_sizes, int n_in,
                              void* d_out, int out_size, void* d_ws, size_t ws_size,
                              hipStream_t stream)
{
    const float* x = (const float*)d_in[0];
    float* out = (float*)d_out;                       // (8,4,256,64,64)
    float* lrh = out + (size_t)33554432;
    float* lrc = lrh + (size_t)2097152;
    float* lrg = lrc + (size_t)2097152;

    char* ws = (char*)d_ws;
    u16* convx = (u16*)ws;                            // 35,651,584 B
    size_t off = 35651584 + 4096;
    u16* cT_a = (u16*)(ws + off); off += 2230272;
    u16* cT_b = (u16*)(ws + off); off += 2230272;
    u16* XT   = (u16*)(ws + off); off += 53526528;    // 32*4356*192*2
    u16* Wr   = (u16*)(ws + off); off += 645120;
    unsigned* bar = (unsigned*)(ws + off);

    hipMemsetAsync(XT, 0, 53526528, stream);
    hipMemsetAsync(cT_b, 0, 2230272, stream);
    transpose_halo<<<dim3(16, 1, 32), 256, 0, stream>>>(x, XT, 32);

    for (int l = 0; l < 4; ++l) {
        const float* wf = (const float*)d_in[1 + 4 * l];
        const float* bf = (const float*)d_in[2 + 4 * l];
        const float* wb = (const float*)d_in[3 + 4 * l];
        const float* bb = (const float*)d_in[4 + 4 * l];
        int cin = (l == 0) ? 32 : 64 * l;
        int ci_total = cin + 32;

        prep_w<<<dim3((2 * 9 * 80 * ci_total + 255) / 256), 256, 0, stream>>>(wf, wb, Wr, ci_total);
        convx_mfma<<<dim3(16, 1, 64), 256, 0, stream>>>(XT, Wr, bf, bb, convx, cin, ci_total);

        hipMemsetAsync(cT_a, 0, 2230272, stream);
        hipMemsetAsync(bar, 0, 4, stream);
        rec_persist<<<dim3(256), 256, 0, stream>>>(
            cT_a, cT_b, Wr, convx, out, lrh, lrc, lrg, XT, bar, cin, ci_total, l);
    }
}

// Round 6
// 616.371 us; speedup vs baseline: 2.4402x; 2.4402x over previous
//
#include <hip/hip_runtime.h>
#include <math.h>

#define T_STEPS 8
#define HW 4096
#define XSTR 192                    // XT channel stride (fixed, max cin)
#define FR_ROW 4352                 // convx u16 per (img,row)

typedef unsigned short u16;
typedef __attribute__((ext_vector_type(8))) short short8;
typedef __attribute__((ext_vector_type(4))) short short4v;
typedef __attribute__((ext_vector_type(4))) float f32x4;

__device__ __forceinline__ u16 f2bf(float f) {
    unsigned u = __builtin_bit_cast(unsigned, f);
    u += 0x7fffu + ((u >> 16) & 1u);
    return (u16)(u >> 16);
}
__device__ __forceinline__ float bf2f(u16 h) {
    unsigned u = ((unsigned)h) << 16;
    return __builtin_bit_cast(float, u);
}
__device__ __forceinline__ float ftanh(float x) {
    float e = __expf(2.f * x);
    return 1.f - 2.f * __builtin_amdgcn_rcpf(e + 1.f);
}
__device__ __forceinline__ float fsigm(float x) {
    return __builtin_amdgcn_rcpf(1.f + __expf(-x));
}

// ---------------------------------------------------------------------------
// l0 only: fp32 x [img][32][64][64] -> bf16 XT[img][66][66][192] ch 0..31
// ---------------------------------------------------------------------------
__global__ __launch_bounds__(256) void transpose_halo(
    const float* __restrict__ src, u16* __restrict__ XT, int src_ctot)
{
    __shared__ float tile[32][257];
    const int img = blockIdx.z;
    const int px0 = blockIdx.x * 256;
    const float* s = src + (size_t)img * src_ctot * HW + px0;
    #pragma unroll
    for (int c = 0; c < 32; ++c)
        tile[c][threadIdx.x] = s[(size_t)c * HW + threadIdx.x];
    __syncthreads();
    const int c = threadIdx.x & 31, pb = threadIdx.x >> 5;
    const int r0 = px0 >> 6;
    for (int p = pb; p < 256; p += 8) {
        int row = r0 + (p >> 6), col = p & 63;
        XT[((size_t)img * 4356 + (row + 1) * 66 + col + 1) * XSTR + c] = f2bf(tile[c][p]);
    }
}

// ---------------------------------------------------------------------------
// Pack weights: Wr[dir][tap][80][ci_total] bf16 (rows >= 65 zeroed)
// ---------------------------------------------------------------------------
__global__ __launch_bounds__(256) void prep_w(
    const float* __restrict__ wf, const float* __restrict__ wb,
    u16* __restrict__ Wr, int ci_total)
{
    int idx = blockIdx.x * 256 + threadIdx.x;
    int total = 2 * 9 * 80 * ci_total;
    if (idx >= total) return;
    int ci = idx % ci_total;
    int rest = idx / ci_total;
    int co = rest % 80; rest /= 80;
    int tap = rest % 9;
    int dir = rest / 9;
    const float* w = dir ? wb : wf;
    float v = (co < 65) ? w[((size_t)co * ci_total + ci) * 9 + tap] : 0.f;
    Wr[idx] = f2bf(v);
}

// ---------------------------------------------------------------------------
// MFMA x-conv, dir-fused: 8 waves = 4 rows x 2 dirs share one LDS stage.
// Per ch-chunk stage [6 rows][66 px][32 ch] bf16, reuse across 9 taps x 8 wv.
// ---------------------------------------------------------------------------
__global__ __launch_bounds__(512, 2) void convx_mfma(
    const u16* __restrict__ XT, const u16* __restrict__ Wr,
    const float* __restrict__ b_f, const float* __restrict__ b_b,
    u16* __restrict__ convx, int cin, int ci_total)
{
    __shared__ u16 xs[6 * 66 * 32];       // 25,344 B
    const int tid = threadIdx.x;
    const int l = tid & 63, wv = tid >> 6;   // 8 waves
    const int g = l >> 4, ln16 = l & 15;
    const int img = blockIdx.z;              // t*4 + b
    const int dir = wv & 1;
    const int wrow = wv >> 1;                // 0..3
    const int r0  = blockIdx.x * 4;
    const int orow = r0 + wrow;

    const float* bias = dir ? b_b : b_f;
    f32x4 acc[5][4];
    #pragma unroll
    for (int mt = 0; mt < 5; ++mt)
        #pragma unroll
        for (int r = 0; r < 4; ++r) {
            int co = mt * 16 + g * 4 + r;
            float bv = (co < 65) ? bias[co] : 0.f;
            #pragma unroll
            for (int nt = 0; nt < 4; ++nt) acc[mt][nt][r] = bv;
        }

    const u16* wdir = Wr + (size_t)dir * 9 * 80 * ci_total + g * 8;
    const u16* xim  = XT + (size_t)img * 4356 * XSTR;

    for (int ch = 0; ch < cin; ch += 32) {
        __syncthreads();
        // stage rows r0..r0+5, 66 px, 32 ch -> 1584 x 16B across 512 threads
        #pragma unroll
        for (int k = 0; k < 4; ++k) {
            int idx = k * 512 + tid;
            if (idx < 1584) {
                int seg = idx & 3;
                int pr  = idx >> 2;
                short8 v = *(const short8*)(xim + (size_t)(r0 * 66 + pr) * XSTR + ch + seg * 8);
                *(short8*)(xs + (size_t)idx * 8) = v;
            }
        }
        __syncthreads();

        #pragma unroll
        for (int ky = 0; ky < 3; ++ky) {
            #pragma unroll
            for (int kx = 0; kx < 3; ++kx) {
                const int tap = ky * 3 + kx;
                const u16* xb = xs + ((size_t)((wrow + ky) * 66 + ln16 + kx)) * 32 + g * 8;
                short8 bv0 = *(const short8*)(xb);
                short8 bv1 = *(const short8*)(xb + 16 * 32);
                short8 bv2 = *(const short8*)(xb + 32 * 32);
                short8 bv3 = *(const short8*)(xb + 48 * 32);
                const u16* wb_ = wdir + ((size_t)tap * 80 + ln16) * ci_total + ch;
                #pragma unroll
                for (int mt = 0; mt < 5; ++mt) {
                    short8 af = *(const short8*)(wb_ + (size_t)mt * 16 * ci_total);
                    acc[mt][0] = __builtin_amdgcn_mfma_f32_16x16x32_bf16(af, bv0, acc[mt][0], 0, 0, 0);
                    acc[mt][1] = __builtin_amdgcn_mfma_f32_16x16x32_bf16(af, bv1, acc[mt][1], 0, 0, 0);
                    acc[mt][2] = __builtin_amdgcn_mfma_f32_16x16x32_bf16(af, bv2, acc[mt][2], 0, 0, 0);
                    acc[mt][3] = __builtin_amdgcn_mfma_f32_16x16x32_bf16(af, bv3, acc[mt][3], 0, 0, 0);
                }
            }
        }
    }

    const int zimg = dir * 32 + img;
    u16* cb = convx + ((size_t)zimg * 64 + orow) * FR_ROW;
    #pragma unroll
    for (int mt = 0; mt < 4; ++mt)
        #pragma unroll
        for (int nt = 0; nt < 4; ++nt) {
            short4v pk;
            #pragma unroll
            for (int r = 0; r < 4; ++r) pk[r] = (short)f2bf(acc[mt][nt][r]);
            *(short4v*)(cb + (size_t)(nt * 4 + mt) * 256 + l * 4) = pk;
        }
    if (g == 0) {
        #pragma unroll
        for (int nt = 0; nt < 4; ++nt) {
            short4v pk;
            #pragma unroll
            for (int r = 0; r < 4; ++r) pk[r] = (short)f2bf(acc[4][nt][r]);
            *(short4v*)(cb + 4096 + nt * 64 + ln16 * 4) = pk;
        }
    }
}

// ---------------------------------------------------------------------------
// Recurrent step, fused: acc = convx + conv(c_prev); A = tanh(acc);
// h -> out fp32 (+XT bf16 slice for next layer, +lr_h), gate=sigm(A[64]),
// c = gate*cand -> cT_out (+lr_c, lr_g). Wave = 1 row x 32 cols x 80 co.
// ---------------------------------------------------------------------------
__global__ __launch_bounds__(256) void rec_mfma(
    const u16* __restrict__ cT_in, u16* __restrict__ cT_out,
    const u16* __restrict__ Wr, const u16* __restrict__ convx,
    float* __restrict__ out_t,
    float* __restrict__ lrh, float* __restrict__ lrc, float* __restrict__ lrg,
    u16* __restrict__ XT,
    int cin, int ci_total, int layer, int step)
{
    const int tid = threadIdx.x;
    const int l = tid & 63, wv = tid >> 6;
    const int g = l >> 4, ln16 = l & 15;
    const int z = blockIdx.z;                  // dir*4 + b
    const int dir = z >> 2, b = z & 3;
    const int t = dir ? (7 - step) : step;
    const int row  = blockIdx.x * 2 + (wv >> 1);
    const int nb   = (wv & 1) * 2;
    const int col0 = nb * 16;

    // init acc from convx fragments (coalesced)
    const int zimg = dir * 32 + t * 4 + b;
    const u16* cxb = convx + ((size_t)zimg * 64 + row) * FR_ROW;
    f32x4 acc[5][2];
    #pragma unroll
    for (int mt = 0; mt < 4; ++mt)
        #pragma unroll
        for (int nt = 0; nt < 2; ++nt) {
            short4v pk = *(const short4v*)(cxb + (size_t)((nb + nt) * 4 + mt) * 256 + l * 4);
            #pragma unroll
            for (int r = 0; r < 4; ++r) acc[mt][nt][r] = bf2f((u16)pk[r]);
        }
    #pragma unroll
    for (int nt = 0; nt < 2; ++nt) {
        if (g == 0) {
            short4v pk = *(const short4v*)(cxb + 4096 + (nb + nt) * 64 + ln16 * 4);
            #pragma unroll
            for (int r = 0; r < 4; ++r) acc[4][nt][r] = bf2f((u16)pk[r]);
        } else {
            #pragma unroll
            for (int r = 0; r < 4; ++r) acc[4][nt][r] = 0.f;
        }
    }

    const u16* wdir = Wr + (size_t)dir * 9 * 80 * ci_total + cin + g * 8;
    const u16* cim  = cT_in + (size_t)z * 4356 * 32 + g * 8;

    #pragma unroll
    for (int ky = 0; ky < 3; ++ky) {
        #pragma unroll
        for (int kx = 0; kx < 3; ++kx) {
            const int tap = ky * 3 + kx;
            const u16* xb_ = cim + (size_t)((row + ky) * 66 + col0 + ln16 + kx) * 32;
            short8 bv0 = *(const short8*)(xb_);
            short8 bv1 = *(const short8*)(xb_ + 16 * 32);
            const u16* wb_ = wdir + ((size_t)tap * 80 + ln16) * ci_total;
            #pragma unroll
            for (int mt = 0; mt < 5; ++mt) {
                short8 af = *(const short8*)(wb_ + (size_t)mt * 16 * ci_total);
                acc[mt][0] = __builtin_amdgcn_mfma_f32_16x16x32_bf16(af, bv0, acc[mt][0], 0, 0, 0);
                acc[mt][1] = __builtin_amdgcn_mfma_f32_16x16x32_bf16(af, bv1, acc[mt][1], 0, 0, 0);
            }
        }
    }

    const bool last_f = (dir == 0) && (step == 7);
    float val[2], gv[2];
    #pragma unroll
    for (int nt = 0; nt < 2; ++nt) {
        val[nt] = fsigm(ftanh(acc[4][nt][0]));
        gv[nt]  = __shfl(val[nt], ln16);       // broadcast from g==0 lanes
    }

    const size_t obase = (size_t)(t * 4 + b) * 256 + 64 * layer + dir * 32;
    const int chb = 64 * layer + dir * 32;
    #pragma unroll
    for (int mt = 0; mt < 2; ++mt)
        #pragma unroll
        for (int nt = 0; nt < 2; ++nt) {
            int px = row * 64 + col0 + nt * 16 + ln16;
            short4v pkh;
            #pragma unroll
            for (int r = 0; r < 4; ++r) {
                int co = mt * 16 + g * 4 + r;
                float v = ftanh(acc[mt][nt][r]);
                out_t[(obase + co) * HW + px] = v;
                pkh[r] = (short)f2bf(v);
                if (last_f) lrh[((size_t)(layer * 4 + b) * 32 + co) * HW + px] = v;
            }
            if (layer < 3)
                *(short4v*)(XT + ((size_t)(t * 4 + b) * 4356 + (row + 1) * 66 +
                                  (col0 + nt * 16 + ln16 + 1)) * XSTR + chb + mt * 16 + g * 4) = pkh;
        }
    #pragma unroll
    for (int mt = 2; mt < 4; ++mt)
        #pragma unroll
        for (int nt = 0; nt < 2; ++nt) {
            short4v pk;
            #pragma unroll
            for (int r = 0; r < 4; ++r) {
                int k = (mt - 2) * 16 + g * 4 + r;
                float c = gv[nt] * ftanh(acc[mt][nt][r]);
                pk[r] = (short)f2bf(c);
                if (last_f)
                    lrc[((size_t)(layer * 4 + b) * 32 + k) * HW + row * 64 + col0 + nt * 16 + ln16] = c;
            }
            int colh = col0 + nt * 16 + ln16 + 1;
            *(short4v*)(cT_out + ((size_t)z * 4356 + (row + 1) * 66 + colh) * 32 + (mt - 2) * 16 + g * 4) = pk;
        }
    if (last_f && g == 0) {
        #pragma unroll
        for (int nt = 0; nt < 2; ++nt)
            lrg[(size_t)(layer * 4 + b) * HW + row * 64 + col0 + nt * 16 + ln16] = val[nt];
    }
}

extern "C" void kernel_launch(void* const* d_in, const int* in_sizes, int n_in,
                              void* d_out, int out_size, void* d_ws, size_t ws_size,
                              hipStream_t stream)
{
    const float* x = (const float*)d_in[0];
    float* out = (float*)d_out;                       // (8,4,256,64,64)
    float* lrh = out + (size_t)33554432;
    float* lrc = lrh + (size_t)2097152;
    float* lrg = lrc + (size_t)2097152;

    char* ws = (char*)d_ws;
    u16* convx = (u16*)ws;                            // 35,651,584 B
    size_t off = 35651584 + 4096;
    u16* cT_a = (u16*)(ws + off); off += 2230272;
    u16* cT_b = (u16*)(ws + off); off += 2230272;
    u16* XT   = (u16*)(ws + off); off += 53526528;    // 32*4356*192*2
    u16* Wr   = (u16*)(ws + off);                     // 645,120 B

    hipMemsetAsync(XT, 0, 53526528, stream);
    hipMemsetAsync(cT_b, 0, 2230272, stream);
    transpose_halo<<<dim3(16, 1, 32), 256, 0, stream>>>(x, XT, 32);

    for (int l = 0; l < 4; ++l) {
        const float* wf = (const float*)d_in[1 + 4 * l];
        const float* bf = (const float*)d_in[2 + 4 * l];
        const float* wb = (const float*)d_in[3 + 4 * l];
        const float* bb = (const float*)d_in[4 + 4 * l];
        int cin = (l == 0) ? 32 : 64 * l;
        int ci_total = cin + 32;

        prep_w<<<dim3((2 * 9 * 80 * ci_total + 255) / 256), 256, 0, stream>>>(wf, wb, Wr, ci_total);
        convx_mfma<<<dim3(16, 1, 32), 512, 0, stream>>>(XT, Wr, bf, bb, convx, cin, ci_total);

        hipMemsetAsync(cT_a, 0, 2230272, stream);
        for (int s = 0; s < 8; ++s) {
            const u16* cin_p = (s & 1) ? cT_b : cT_a;
            u16* cout_p      = (s & 1) ? cT_a : cT_b;
            rec_mfma<<<dim3(32, 1, 8), 256, 0, stream>>>(
                cin_p, cout_p, Wr, convx, out, lrh, lrc, lrg, XT, cin, ci_total, l, s);
        }
    }
}